// Round 1
// baseline (303.707 us; speedup 1.0000x reference)
//
#include <hip/hip_runtime.h>

#define N_    8192
#define T_    20
#define M_    6
#define D_    9
#define NM_   (N_*M_)        // 49152 LSTM chains
#define NMP_  (NM_/2)        // 24576 chain PAIRS
#define NT_   (N_*T_)        // 163840 GNN problems
#define NTM7_ (N_*T_*M_*7)   // 6881280 elements per output tensor

#define LOG2E 1.44269504088896f

typedef __attribute__((ext_vector_type(2))) float v2f;

// native-rate activations: v_exp_f32 + v_rcp_f32 (no IEEE div sequence)
__device__ __forceinline__ float sigm(float x){
    return __builtin_amdgcn_rcpf(1.f + __builtin_amdgcn_exp2f(-LOG2E * x));
}
__device__ __forceinline__ float tanh_(float x){
    return fmaf(2.f, __builtin_amdgcn_rcpf(1.f + __builtin_amdgcn_exp2f(-2.f*LOG2E * x)), -1.f);
}
__device__ __forceinline__ v2f splat(float s){ return (v2f){s, s}; }
__device__ __forceinline__ v2f sigm2(v2f x){ v2f r; r.x = sigm(x.x); r.y = sigm(x.y); return r; }
__device__ __forceinline__ v2f tanh2(v2f x){ v2f r; r.x = tanh_(x.x); r.y = tanh_(x.y); return r; }
__device__ __forceinline__ v2f relu2(v2f x){ v2f r; r.x = fmaxf(x.x,0.f); r.y = fmaxf(x.y,0.f); return r; }

// ---------------------------------------------------------------------------
// Kernel A: GNN (unchanged — verified at R8)
// ---------------------------------------------------------------------------
__global__ __launch_bounds__(64) void k_gnn(
    const float* __restrict__ nf,    // (N,T,M,3)
    const float* __restrict__ pos,   // (N,T,M,6)
    const float* __restrict__ am,    // (N,T,M,M)
    const float* __restrict__ msgW, const float* __restrict__ msgb,
    const float* __restrict__ gWih, const float* __restrict__ gWhh,
    const float* __restrict__ gbih, const float* __restrict__ gbhh,
    const float* __restrict__ ro1W, const float* __restrict__ ro1b,
    const float* __restrict__ ro2W, const float* __restrict__ ro2b,
    const int*   __restrict__ numrec,
    float* __restrict__ hid,         // [nm][t][d]
    float* __restrict__ out0)        // pred_label0 region
{
    __shared__ v2f mbuf[11 * 58];    // 5104 B; row 10 = dummy for lanes 60..63

    const int lane = threadIdx.x & 63;
    const int g    = lane / 6;
    const int i    = lane - g * 6;
    const int gB   = g * 58;
    const bool lactive = (lane < 60);

    const int wbase = blockIdx.x * 20;
    const int ntA = lactive ? (wbase + g)      : 0;
    const int ntB = lactive ? (wbase + 10 + g) : 0;
    const int nA = ntA / T_, tA = ntA - nA * T_;
    const int nB = ntB / T_, tB = ntB - nB * T_;

    v2f s[D_];
    {
        const float* pA = nf + (size_t)ntA * 18 + i * 3;
        const float* pB = nf + (size_t)ntB * 18 + i * 3;
        #pragma unroll
        for (int k = 0; k < 3; ++k) { s[k].x = pA[k]; s[k].y = pB[k]; }
    }
    {
        const float2* pA = (const float2*)(pos + (size_t)ntA * 36 + i * 6);
        const float2* pB = (const float2*)(pos + (size_t)ntB * 36 + i * 6);
        #pragma unroll
        for (int k = 0; k < 3; ++k) {
            float2 a = pA[k], b = pB[k];
            s[3 + 2*k]     = (v2f){a.x, b.x};
            s[3 + 2*k + 1] = (v2f){a.y, b.y};
        }
    }
    v2f attr[M_];
    {
        const float2* pA = (const float2*)(am + (size_t)ntA * 36 + i * 6);
        const float2* pB = (const float2*)(am + (size_t)ntB * 36 + i * 6);
        #pragma unroll
        for (int k = 0; k < 3; ++k) {
            float2 a = pA[k], b = pB[k];
            attr[2*k]     = (v2f){a.x, b.x};
            attr[2*k + 1] = (v2f){a.y, b.y};
        }
    }
    const int nrA = numrec[nA * T_];
    const int nrB = numrec[nB * T_];
    #pragma unroll
    for (int q = 0; q < M_; ++q) {
        attr[q].x *= (q < nrA) ? 1.f : 0.f;
        attr[q].y *= (q < nrB) ? 1.f : 0.f;
    }
    v2f vmi; vmi.x = (i < nrA) ? 1.f : 0.f; vmi.y = (i < nrB) ? 1.f : 0.f;

    #pragma unroll
    for (int it = 0; it < 2; ++it) {
        #pragma unroll
        for (int d = 0; d < D_; ++d) {
            v2f a = splat(msgb[d]);
            #pragma unroll
            for (int k = 0; k < D_; ++k) a += s[k] * msgW[d*9 + k];
            mbuf[gB + d*6 + i] = a;
        }
        v2f mm[D_];
        #pragma unroll
        for (int d = 0; d < D_; ++d) {
            const float4* rp = (const float4*)&mbuf[gB + d*6];
            float4 p0 = rp[0], p1 = rp[1], p2 = rp[2];
            v2f a = attr[0] * (v2f){p0.x, p0.y};
            a += attr[1] * (v2f){p0.z, p0.w};
            a += attr[2] * (v2f){p1.x, p1.y};
            a += attr[3] * (v2f){p1.z, p1.w};
            a += attr[4] * (v2f){p2.x, p2.y};
            a += attr[5] * (v2f){p2.z, p2.w};
            mm[d] = a;
        }
        v2f grz[18], gxn[9], ghn[9];
        #pragma unroll
        for (int j = 0; j < 18; ++j) {
            v2f a = splat(gbih[j] + gbhh[j]);
            #pragma unroll
            for (int k = 0; k < D_; ++k) {
                a += mm[k] * gWih[j*9 + k];
                a += s[k]  * gWhh[j*9 + k];
            }
            grz[j] = a;
        }
        #pragma unroll
        for (int j = 0; j < 9; ++j) {
            v2f ax = splat(gbih[18 + j]), ah = splat(gbhh[18 + j]);
            #pragma unroll
            for (int k = 0; k < D_; ++k) {
                ax += mm[k] * gWih[(18 + j)*9 + k];
                ah += s[k]  * gWhh[(18 + j)*9 + k];
            }
            gxn[j] = ax; ghn[j] = ah;
        }
        #pragma unroll
        for (int d = 0; d < D_; ++d) {
            v2f r  = sigm2(grz[d]);
            v2f z  = sigm2(grz[9 + d]);
            v2f nn = tanh2(gxn[d] + r * ghn[d]);
            s[d] = vmi * ((splat(1.f) - z) * nn + z * s[d]);
        }
    }

    if (lactive) {
        float* hpA = hid + (size_t)(nA * M_ + i) * (T_ * D_) + tA * D_;
        float* hpB = hid + (size_t)(nB * M_ + i) * (T_ * D_) + tB * D_;
        #pragma unroll
        for (int d = 0; d < D_; ++d) { hpA[d] = s[d].x; hpB[d] = s[d].y; }
    }

    v2f q9[D_];
    #pragma unroll
    for (int d = 0; d < D_; ++d) {
        v2f a = splat(ro1b[d]);
        #pragma unroll
        for (int k = 0; k < D_; ++k) a += s[k] * ro1W[d*9 + k];
        q9[d] = relu2(a);
    }
    if (lactive) {
        float* opA = out0 + (size_t)ntA * 42 + i * 7;
        float* opB = out0 + (size_t)ntB * 42 + i * 7;
        #pragma unroll
        for (int j = 0; j < 7; ++j) {
            v2f a = splat(ro2b[j]);
            #pragma unroll
            for (int k = 0; k < D_; ++k) a += q9[k] * ro2W[j*9 + k];
            a *= vmi;
            opA[j] = a.x; opB[j] = a.y;
        }
    }
}

// ---------------------------------------------------------------------------
// Kernel B (R9): bidirectional LSTM, packed fp32 — TWO chains per lane (v2f).
// Restructure vs R8: backward scan runs FIRST and stores only hb in LDS
// (hbv, 11.5 KB). The forward scan FUSES the readout: at step t the hxs4
// b128 broadcast already delivers hf[t-1] to every lane of the group, so
// the lr1->relu->lr2 readout for time t-1 runs inline (hb half read from
// hbv, q exchanged through a 512 B qbuf, lanes d<7 emit the 7 outputs).
// hf is never stored; the 24 KB hstv buffer and the deferred-readout phase
// are gone.  LDS 26112 -> 13504 B  => 6 -> 12 single-wave blocks/CU.
// Readout FLOPs are recurrence-independent, so they fill the scan's
// dependency stalls. All new LDS patterns are group-broadcast,
// conflict-free mod 32 banks.
// ---------------------------------------------------------------------------
__global__ __launch_bounds__(64) void k_lstm(
    const float* __restrict__ hid,   // [nm][t][d]
    const float* __restrict__ fWih, const float* __restrict__ fWhh,
    const float* __restrict__ fbih, const float* __restrict__ fbhh,
    const float* __restrict__ bWih, const float* __restrict__ bWhh,
    const float* __restrict__ bbih, const float* __restrict__ bbhh,
    const float* __restrict__ lr1W, const float* __restrict__ lr1b,
    const float* __restrict__ lr2W, const float* __restrict__ lr2b,
    const int*   __restrict__ numrec,
    float* __restrict__ out)         // pred_label region
{
    __shared__ float4 hxs4[8 * 11];  //  1408 B: [row][j] {hA,hB,xA,xB}
    __shared__ v2f    hbv [8 * 181]; // 11584 B: [row][t*9 + d] = hb[t][d]
    __shared__ v2f    qbuf[64];      //   512 B: [row*9 + d] = relu(lr1(...))

    const int lane = threadIdx.x & 63;
    const int grp0 = lane / 9;                 // 0..7 (7 == lane 63 only)
    const int d    = lane - grp0 * 9;
    const int row  = grp0;                     // row 7 = dummy

    bool active = (grp0 < 7);
    int pi = blockIdx.x * 7 + (active ? grp0 : 0);
    active = active && (pi < NMP_);
    const int pair = active ? pi : 0;
    const int cA = pair * 2, cB = cA + 1;

    const float* xbA = hid + (size_t)cA * (T_ * D_);
    const float* xbB = hid + (size_t)cB * (T_ * D_);
    const int xrow  = row * 11;
    const int hbrow = row * 181;
    const int qrow  = row * 9;                 // lane63: qrow+d = 63 (safe slot)

    // ---- pair metadata for the fused readout ----
    const int nA2 = cA / M_, mA2 = cA - nA2 * M_;
    const int nB2 = cB / M_, mB2 = cB - nB2 * M_;
    v2f vi;
    vi.x = (mA2 < numrec[nA2 * T_]) ? 1.f : 0.f;
    vi.y = (mB2 < numrec[nB2 * T_]) ? 1.f : 0.f;
    float* oA = out + (size_t)nA2 * (T_ * M_ * 7) + mA2 * 7;
    float* oB = out + (size_t)nB2 * (T_ * M_ * 7) + mB2 * 7;

    // ---- readout weights (held in VGPRs through the forward scan) ----
    const int j7 = (d < 7) ? d : 0;
    float w1[18], w2[9];
    #pragma unroll
    for (int k = 0; k < 18; ++k) w1[k] = lr1W[d * 18 + k];
    #pragma unroll
    for (int k = 0; k < 9; ++k)  w2[k] = lr2W[j7 * 9 + k];
    const float b1 = lr1b[d];
    const float b2 = lr2b[j7];

    // ---------------- backward scan (first: fills hbv) ----------------
    {
        float wxi[9], wxf[9], wxg[9], wxo[9], whi[9], whf[9], whg[9], who[9];
        #pragma unroll
        for (int k = 0; k < 9; ++k) {
            wxi[k] = bWih[(d     )*9 + k];  whi[k] = bWhh[(d     )*9 + k];
            wxf[k] = bWih[(9  + d)*9 + k];  whf[k] = bWhh[(9  + d)*9 + k];
            wxg[k] = bWih[(18 + d)*9 + k];  whg[k] = bWhh[(18 + d)*9 + k];
            wxo[k] = bWih[(27 + d)*9 + k];  who[k] = bWhh[(27 + d)*9 + k];
        }
        const float bi = bbih[d]      + bbhh[d];
        const float bf = bbih[9 + d]  + bbhh[9 + d];
        const float bg = bbih[18 + d] + bbhh[18 + d];
        const float bo = bbih[27 + d] + bbhh[27 + d];

        hxs4[xrow + d] = make_float4(0.f, 0.f, xbA[19*9 + d], xbB[19*9 + d]);
        v2f h = splat(0.f), c = splat(0.f);
        for (int tt = T_ - 1; tt >= 0; --tt) {
            const float xnA = (tt > 0) ? xbA[(tt-1)*9 + d] : 0.f;
            const float xnB = (tt > 0) ? xbB[(tt-1)*9 + d] : 0.f;
            v2f gi = splat(bi), gf = splat(bf), gg = splat(bg), go = splat(bo);
            #pragma unroll
            for (int j = 0; j < 9; ++j) {
                float4 v = hxs4[xrow + j];                 // broadcast b128
                v2f hj = (v2f){v.x, v.y}, xj = (v2f){v.z, v.w};
                gi += hj * whi[j]; gi += xj * wxi[j];
                gf += hj * whf[j]; gf += xj * wxf[j];
                gg += hj * whg[j]; gg += xj * wxg[j];
                go += hj * who[j]; go += xj * wxo[j];
            }
            c = sigm2(gf) * c + sigm2(gi) * tanh2(gg);
            h = sigm2(go) * tanh2(c);                      // hb[tt]
            hbv[hbrow + tt*9 + d] = h;                     // save hb[tt]
            hxs4[xrow + d] = make_float4(h.x, h.y, xnA, xnB);
        }
    }

    // ---------------- forward scan + fused readout ----------------
    {
        float wxi[9], wxf[9], wxg[9], wxo[9], whi[9], whf[9], whg[9], who[9];
        #pragma unroll
        for (int k = 0; k < 9; ++k) {
            wxi[k] = fWih[(d     )*9 + k];  whi[k] = fWhh[(d     )*9 + k];
            wxf[k] = fWih[(9  + d)*9 + k];  whf[k] = fWhh[(9  + d)*9 + k];
            wxg[k] = fWih[(18 + d)*9 + k];  whg[k] = fWhh[(18 + d)*9 + k];
            wxo[k] = fWih[(27 + d)*9 + k];  who[k] = fWhh[(27 + d)*9 + k];
        }
        const float bi = fbih[d]      + fbhh[d];
        const float bf = fbih[9 + d]  + fbhh[9 + d];
        const float bg = fbih[18 + d] + fbhh[18 + d];
        const float bo = fbih[27 + d] + fbhh[27 + d];

        hxs4[xrow + d] = make_float4(0.f, 0.f, xbA[d], xbB[d]);  // {h(-1), x0}
        v2f h = splat(0.f), c = splat(0.f);
        for (int t = 0; t < T_; ++t) {
            const float xnA = (t < T_-1) ? xbA[(t+1)*9 + d] : 0.f;
            const float xnB = (t < T_-1) ? xbB[(t+1)*9 + d] : 0.f;

            // readout (time t-1): start q with the hb half so the LDS
            // reads overlap the gate math below.
            v2f q = splat(b1);
            if (t > 0) {
                const int hb0 = hbrow + (t - 1) * 9;
                #pragma unroll
                for (int k = 0; k < 9; ++k) q += hbv[hb0 + k] * w1[9 + k];
            }

            v2f gi = splat(bi), gf = splat(bf), gg = splat(bg), go = splat(bo);
            v2f hjs[9];
            #pragma unroll
            for (int j = 0; j < 9; ++j) {
                float4 v = hxs4[xrow + j];                 // broadcast b128
                v2f hj = (v2f){v.x, v.y}, xj = (v2f){v.z, v.w};
                hjs[j] = hj;                               // == hf[t-1][j]
                gi += hj * whi[j]; gi += xj * wxi[j];
                gf += hj * whf[j]; gf += xj * wxf[j];
                gg += hj * whg[j]; gg += xj * wxg[j];
                go += hj * who[j]; go += xj * wxo[j];
            }

            if (t > 0) {                                   // finish readout t-1
                #pragma unroll
                for (int k = 0; k < 9; ++k) q += hjs[k] * w1[k];
                q = relu2(q);
                qbuf[qrow + d] = q;                        // wave-sync exchange
                if (active && (d < 7)) {
                    v2f a = splat(b2);
                    #pragma unroll
                    for (int k = 0; k < 9; ++k) a += qbuf[qrow + k] * w2[k];
                    a *= vi;
                    const int ot = (t - 1) * (M_ * 7);
                    oA[ot + d] = a.x;  oB[ot + d] = a.y;
                }
            }

            c = sigm2(gf) * c + sigm2(gi) * tanh2(gg);
            h = sigm2(go) * tanh2(c);
            hxs4[xrow + d] = make_float4(h.x, h.y, xnA, xnB);  // {h_t, x_{t+1}}
        }

        // readout for t = 19 (hf[19] was just published to hxs4)
        {
            v2f q = splat(b1);
            const int hb0 = hbrow + 19 * 9;
            #pragma unroll
            for (int k = 0; k < 9; ++k) q += hbv[hb0 + k] * w1[9 + k];
            #pragma unroll
            for (int k = 0; k < 9; ++k) {
                float4 v = hxs4[xrow + k];
                q += (v2f){v.x, v.y} * w1[k];
            }
            q = relu2(q);
            qbuf[qrow + d] = q;
            if (active && (d < 7)) {
                v2f a = splat(b2);
                #pragma unroll
                for (int k = 0; k < 9; ++k) a += qbuf[qrow + k] * w2[k];
                a *= vi;
                const int ot = 19 * (M_ * 7);
                oA[ot + d] = a.x;  oB[ot + d] = a.y;
            }
        }
    }
}

extern "C" void kernel_launch(void* const* d_in, const int* in_sizes, int n_in,
                              void* d_out, int out_size, void* d_ws, size_t ws_size,
                              hipStream_t stream) {
    const float* nf    = (const float*)d_in[0];
    const float* pos   = (const float*)d_in[1];
    const float* am    = (const float*)d_in[2];
    const float* msgW  = (const float*)d_in[3];
    const float* msgb  = (const float*)d_in[4];
    const float* gWih  = (const float*)d_in[5];
    const float* gWhh  = (const float*)d_in[6];
    const float* gbih  = (const float*)d_in[7];
    const float* gbhh  = (const float*)d_in[8];
    const float* ro1W  = (const float*)d_in[9];
    const float* ro1b  = (const float*)d_in[10];
    const float* ro2W  = (const float*)d_in[11];
    const float* ro2b  = (const float*)d_in[12];
    const float* lfWih = (const float*)d_in[13];
    const float* lfWhh = (const float*)d_in[14];
    const float* lfbih = (const float*)d_in[15];
    const float* lfbhh = (const float*)d_in[16];
    const float* lbWih = (const float*)d_in[17];
    const float* lbWhh = (const float*)d_in[18];
    const float* lbbih = (const float*)d_in[19];
    const float* lbbhh = (const float*)d_in[20];
    const float* lr1W  = (const float*)d_in[21];
    const float* lr1b  = (const float*)d_in[22];
    const float* lr2W  = (const float*)d_in[23];
    const float* lr2b  = (const float*)d_in[24];
    const int* numrec  = (const int*)d_in[25];

    // ws: hidden [nm][t][d] fp32 = 35,389,440 B
    float* hid = (float*)d_ws;

    float* outp = (float*)d_out;           // pred_label
    float* out0 = (float*)d_out + NTM7_;   // pred_label0

    // A: 20 (n,t) per single-wave block (2 per lane) -> 8192 blocks
    k_gnn <<<NT_ / 20, 64, 0, stream>>>(nf, pos, am, msgW, msgb, gWih, gWhh,
                                        gbih, gbhh, ro1W, ro1b, ro2W, ro2b,
                                        numrec, hid, out0);
    // B: 7 chain-pairs per single-wave block -> ceil(24576/7) = 3511 blocks
    const int lgrid = (NMP_ + 6) / 7;
    k_lstm<<<lgrid, 64, 0, stream>>>(hid, lfWih, lfWhh, lfbih, lfbhh,
                                     lbWih, lbWhh, lbbih, lbbhh,
                                     lr1W, lr1b, lr2W, lr2b, numrec, outp);
}

// Round 2
// 274.366 us; speedup vs baseline: 1.1069x; 1.1069x over previous
//
#include <hip/hip_runtime.h>

#define N_    8192
#define T_    20
#define M_    6
#define D_    9
#define NM_   (N_*M_)        // 49152 LSTM chains
#define NMP_  (NM_/2)        // 24576 chain PAIRS
#define NT_   (N_*T_)        // 163840 GNN problems
#define NTM7_ (N_*T_*M_*7)   // 6881280 elements per output tensor

#define LOG2E 1.44269504088896f

typedef __attribute__((ext_vector_type(2))) float v2f;

// native-rate activations: v_exp_f32 + v_rcp_f32 (no IEEE div sequence)
__device__ __forceinline__ float sigm(float x){
    return __builtin_amdgcn_rcpf(1.f + __builtin_amdgcn_exp2f(-LOG2E * x));
}
__device__ __forceinline__ float tanh_(float x){
    return fmaf(2.f, __builtin_amdgcn_rcpf(1.f + __builtin_amdgcn_exp2f(-2.f*LOG2E * x)), -1.f);
}
__device__ __forceinline__ v2f splat(float s){ return (v2f){s, s}; }
__device__ __forceinline__ v2f sigm2(v2f x){ v2f r; r.x = sigm(x.x); r.y = sigm(x.y); return r; }
__device__ __forceinline__ v2f tanh2(v2f x){ v2f r; r.x = tanh_(x.x); r.y = tanh_(x.y); return r; }
__device__ __forceinline__ v2f relu2(v2f x){ v2f r; r.x = fmaxf(x.x,0.f); r.y = fmaxf(x.y,0.f); return r; }

// ---------------------------------------------------------------------------
// Kernel A: GNN (unchanged — verified at R8)
// ---------------------------------------------------------------------------
__global__ __launch_bounds__(64) void k_gnn(
    const float* __restrict__ nf,    // (N,T,M,3)
    const float* __restrict__ pos,   // (N,T,M,6)
    const float* __restrict__ am,    // (N,T,M,M)
    const float* __restrict__ msgW, const float* __restrict__ msgb,
    const float* __restrict__ gWih, const float* __restrict__ gWhh,
    const float* __restrict__ gbih, const float* __restrict__ gbhh,
    const float* __restrict__ ro1W, const float* __restrict__ ro1b,
    const float* __restrict__ ro2W, const float* __restrict__ ro2b,
    const int*   __restrict__ numrec,
    float* __restrict__ hid,         // [nm][t][d]
    float* __restrict__ out0)        // pred_label0 region
{
    __shared__ v2f mbuf[11 * 58];    // 5104 B; row 10 = dummy for lanes 60..63

    const int lane = threadIdx.x & 63;
    const int g    = lane / 6;
    const int i    = lane - g * 6;
    const int gB   = g * 58;
    const bool lactive = (lane < 60);

    const int wbase = blockIdx.x * 20;
    const int ntA = lactive ? (wbase + g)      : 0;
    const int ntB = lactive ? (wbase + 10 + g) : 0;
    const int nA = ntA / T_, tA = ntA - nA * T_;
    const int nB = ntB / T_, tB = ntB - nB * T_;

    v2f s[D_];
    {
        const float* pA = nf + (size_t)ntA * 18 + i * 3;
        const float* pB = nf + (size_t)ntB * 18 + i * 3;
        #pragma unroll
        for (int k = 0; k < 3; ++k) { s[k].x = pA[k]; s[k].y = pB[k]; }
    }
    {
        const float2* pA = (const float2*)(pos + (size_t)ntA * 36 + i * 6);
        const float2* pB = (const float2*)(pos + (size_t)ntB * 36 + i * 6);
        #pragma unroll
        for (int k = 0; k < 3; ++k) {
            float2 a = pA[k], b = pB[k];
            s[3 + 2*k]     = (v2f){a.x, b.x};
            s[3 + 2*k + 1] = (v2f){a.y, b.y};
        }
    }
    v2f attr[M_];
    {
        const float2* pA = (const float2*)(am + (size_t)ntA * 36 + i * 6);
        const float2* pB = (const float2*)(am + (size_t)ntB * 36 + i * 6);
        #pragma unroll
        for (int k = 0; k < 3; ++k) {
            float2 a = pA[k], b = pB[k];
            attr[2*k]     = (v2f){a.x, b.x};
            attr[2*k + 1] = (v2f){a.y, b.y};
        }
    }
    const int nrA = numrec[nA * T_];
    const int nrB = numrec[nB * T_];
    #pragma unroll
    for (int q = 0; q < M_; ++q) {
        attr[q].x *= (q < nrA) ? 1.f : 0.f;
        attr[q].y *= (q < nrB) ? 1.f : 0.f;
    }
    v2f vmi; vmi.x = (i < nrA) ? 1.f : 0.f; vmi.y = (i < nrB) ? 1.f : 0.f;

    #pragma unroll
    for (int it = 0; it < 2; ++it) {
        #pragma unroll
        for (int d = 0; d < D_; ++d) {
            v2f a = splat(msgb[d]);
            #pragma unroll
            for (int k = 0; k < D_; ++k) a += s[k] * msgW[d*9 + k];
            mbuf[gB + d*6 + i] = a;
        }
        v2f mm[D_];
        #pragma unroll
        for (int d = 0; d < D_; ++d) {
            const float4* rp = (const float4*)&mbuf[gB + d*6];
            float4 p0 = rp[0], p1 = rp[1], p2 = rp[2];
            v2f a = attr[0] * (v2f){p0.x, p0.y};
            a += attr[1] * (v2f){p0.z, p0.w};
            a += attr[2] * (v2f){p1.x, p1.y};
            a += attr[3] * (v2f){p1.z, p1.w};
            a += attr[4] * (v2f){p2.x, p2.y};
            a += attr[5] * (v2f){p2.z, p2.w};
            mm[d] = a;
        }
        v2f grz[18], gxn[9], ghn[9];
        #pragma unroll
        for (int j = 0; j < 18; ++j) {
            v2f a = splat(gbih[j] + gbhh[j]);
            #pragma unroll
            for (int k = 0; k < D_; ++k) {
                a += mm[k] * gWih[j*9 + k];
                a += s[k]  * gWhh[j*9 + k];
            }
            grz[j] = a;
        }
        #pragma unroll
        for (int j = 0; j < 9; ++j) {
            v2f ax = splat(gbih[18 + j]), ah = splat(gbhh[18 + j]);
            #pragma unroll
            for (int k = 0; k < D_; ++k) {
                ax += mm[k] * gWih[(18 + j)*9 + k];
                ah += s[k]  * gWhh[(18 + j)*9 + k];
            }
            gxn[j] = ax; ghn[j] = ah;
        }
        #pragma unroll
        for (int d = 0; d < D_; ++d) {
            v2f r  = sigm2(grz[d]);
            v2f z  = sigm2(grz[9 + d]);
            v2f nn = tanh2(gxn[d] + r * ghn[d]);
            s[d] = vmi * ((splat(1.f) - z) * nn + z * s[d]);
        }
    }

    if (lactive) {
        float* hpA = hid + (size_t)(nA * M_ + i) * (T_ * D_) + tA * D_;
        float* hpB = hid + (size_t)(nB * M_ + i) * (T_ * D_) + tB * D_;
        #pragma unroll
        for (int d = 0; d < D_; ++d) { hpA[d] = s[d].x; hpB[d] = s[d].y; }
    }

    v2f q9[D_];
    #pragma unroll
    for (int d = 0; d < D_; ++d) {
        v2f a = splat(ro1b[d]);
        #pragma unroll
        for (int k = 0; k < D_; ++k) a += s[k] * ro1W[d*9 + k];
        q9[d] = relu2(a);
    }
    if (lactive) {
        float* opA = out0 + (size_t)ntA * 42 + i * 7;
        float* opB = out0 + (size_t)ntB * 42 + i * 7;
        #pragma unroll
        for (int j = 0; j < 7; ++j) {
            v2f a = splat(ro2b[j]);
            #pragma unroll
            for (int k = 0; k < D_; ++k) a += q9[k] * ro2W[j*9 + k];
            a *= vmi;
            opA[j] = a.x; opB[j] = a.y;
        }
    }
}

// ---------------------------------------------------------------------------
// Kernel B (R10): bidirectional LSTM, packed fp32 — TWO chains per lane (v2f).
// R8 structure (scans + deferred readout, ~108 VGPR) but with TWO waves per
// block: wave 0 runs the forward scan, wave 1 the backward scan for the SAME
// 7 pairs concurrently (the scans are independent), then both waves split the
// 140-item deferred readout (2 rounds of 128). Numerics identical to R8.
// hstv shrunk to 7 rows (lane-63 stores exec-masked, no dummy row):
// LDS = 2*1408 (hxs4) + 21336 (hstv) = 24152 B -> 6 blocks/CU = 12 waves/CU
// (R8: 6 waves/CU, and block serial time ~halves).
// ---------------------------------------------------------------------------
__global__ __launch_bounds__(128) void k_lstm(
    const float* __restrict__ hid,   // [nm][t][d]
    const float* __restrict__ fWih, const float* __restrict__ fWhh,
    const float* __restrict__ fbih, const float* __restrict__ fbhh,
    const float* __restrict__ bWih, const float* __restrict__ bWhh,
    const float* __restrict__ bbih, const float* __restrict__ bbhh,
    const float* __restrict__ lr1W, const float* __restrict__ lr1b,
    const float* __restrict__ lr2W, const float* __restrict__ lr2b,
    const int*   __restrict__ numrec,
    float* __restrict__ out)         // pred_label region
{
    __shared__ float4 hxs4[2][8 * 11]; // 2816 B: per-wave [row][j] {hA,hB,xA,xB}
    __shared__ v2f    hstv[7 * 381];   // 21336 B: [ch][t*19 + d]=hf, [..+9+d]=hb

    const int tid  = threadIdx.x;
    const int wv   = tid >> 6;                 // 0 = forward, 1 = backward
    const int lane = tid & 63;
    const int grp0 = lane / 9;                 // 0..7 (7 == lane 63 only)
    const int d    = lane - grp0 * 9;
    const int row  = grp0;

    bool active = (grp0 < 7);
    int pi = blockIdx.x * 7 + (active ? grp0 : 0);
    active = active && (pi < NMP_);
    const int pair = active ? pi : 0;
    const int cA = pair * 2, cB = cA + 1;

    const float* xbA = hid + (size_t)cA * (T_ * D_);
    const float* xbB = hid + (size_t)cB * (T_ * D_);
    const int  xrow   = row * 11;
    const bool hwrite = (grp0 < 7);            // lane 63 never writes hstv
    const int  hrow   = hwrite ? row * 381 : 0;

    if (wv == 0) {
        // ---------------- forward scan ----------------
        float wxi[9], wxf[9], wxg[9], wxo[9], whi[9], whf[9], whg[9], who[9];
        #pragma unroll
        for (int k = 0; k < 9; ++k) {
            wxi[k] = fWih[(d     )*9 + k];  whi[k] = fWhh[(d     )*9 + k];
            wxf[k] = fWih[(9  + d)*9 + k];  whf[k] = fWhh[(9  + d)*9 + k];
            wxg[k] = fWih[(18 + d)*9 + k];  whg[k] = fWhh[(18 + d)*9 + k];
            wxo[k] = fWih[(27 + d)*9 + k];  who[k] = fWhh[(27 + d)*9 + k];
        }
        const float bi = fbih[d]      + fbhh[d];
        const float bf = fbih[9 + d]  + fbhh[9 + d];
        const float bg = fbih[18 + d] + fbhh[18 + d];
        const float bo = fbih[27 + d] + fbhh[27 + d];

        hxs4[0][xrow + d] = make_float4(0.f, 0.f, xbA[d], xbB[d]);  // {h(-1), x0}
        v2f h = splat(0.f), c = splat(0.f);
        for (int t = 0; t < T_; ++t) {
            const float xnA = (t < T_-1) ? xbA[(t+1)*9 + d] : 0.f;
            const float xnB = (t < T_-1) ? xbB[(t+1)*9 + d] : 0.f;
            v2f gi = splat(bi), gf = splat(bf), gg = splat(bg), go = splat(bo);
            #pragma unroll
            for (int j = 0; j < 9; ++j) {
                float4 v = hxs4[0][xrow + j];              // broadcast b128
                v2f hj = (v2f){v.x, v.y}, xj = (v2f){v.z, v.w};
                gi += hj * whi[j]; gi += xj * wxi[j];
                gf += hj * whf[j]; gf += xj * wxf[j];
                gg += hj * whg[j]; gg += xj * wxg[j];
                go += hj * who[j]; go += xj * wxo[j];
            }
            c = sigm2(gf) * c + sigm2(gi) * tanh2(gg);
            h = sigm2(go) * tanh2(c);
            if (hwrite) hstv[hrow + t*19 + d] = h;         // save hf[t]
            hxs4[0][xrow + d] = make_float4(h.x, h.y, xnA, xnB); // {h_t, x_{t+1}}
        }
    } else {
        // ---------------- backward scan ----------------
        float wxi[9], wxf[9], wxg[9], wxo[9], whi[9], whf[9], whg[9], who[9];
        #pragma unroll
        for (int k = 0; k < 9; ++k) {
            wxi[k] = bWih[(d     )*9 + k];  whi[k] = bWhh[(d     )*9 + k];
            wxf[k] = bWih[(9  + d)*9 + k];  whf[k] = bWhh[(9  + d)*9 + k];
            wxg[k] = bWih[(18 + d)*9 + k];  whg[k] = bWhh[(18 + d)*9 + k];
            wxo[k] = bWih[(27 + d)*9 + k];  who[k] = bWhh[(27 + d)*9 + k];
        }
        const float bi = bbih[d]      + bbhh[d];
        const float bf = bbih[9 + d]  + bbhh[9 + d];
        const float bg = bbih[18 + d] + bbhh[18 + d];
        const float bo = bbih[27 + d] + bbhh[27 + d];

        hxs4[1][xrow + d] = make_float4(0.f, 0.f, xbA[19*9 + d], xbB[19*9 + d]);
        v2f h = splat(0.f), c = splat(0.f);
        for (int tt = T_ - 1; tt >= 0; --tt) {
            const float xnA = (tt > 0) ? xbA[(tt-1)*9 + d] : 0.f;
            const float xnB = (tt > 0) ? xbB[(tt-1)*9 + d] : 0.f;
            v2f gi = splat(bi), gf = splat(bf), gg = splat(bg), go = splat(bo);
            #pragma unroll
            for (int j = 0; j < 9; ++j) {
                float4 v = hxs4[1][xrow + j];              // broadcast b128
                v2f hj = (v2f){v.x, v.y}, xj = (v2f){v.z, v.w};
                gi += hj * whi[j]; gi += xj * wxi[j];
                gf += hj * whf[j]; gf += xj * wxf[j];
                gg += hj * whg[j]; gg += xj * wxg[j];
                go += hj * who[j]; go += xj * wxo[j];
            }
            c = sigm2(gf) * c + sigm2(gi) * tanh2(gg);
            h = sigm2(go) * tanh2(c);                      // hb[tt]
            if (hwrite) hstv[hrow + tt*19 + 9 + d] = h;    // save hb[tt]
            hxs4[1][xrow + d] = make_float4(h.x, h.y, xnA, xnB);
        }
    }

    __syncthreads();

    // ---------------- deferred readout (block-local pair-items) ----------------
    // 140 items per block: item -> (pair 0..6, t 0..19); each item outputs
    // BOTH chains of the pair. 128 threads -> 2 rounds.
    #pragma unroll 1
    for (int rr = 0; rr < 2; ++rr) {
        const int item = rr * 128 + tid;
        if (item >= 140) break;
        const int ch = item / 20;
        const int t  = item - ch * 20;
        const int pi2 = blockIdx.x * 7 + ch;
        if (pi2 >= NMP_) continue;
        const int base = ch * 381 + t * 19;

        v2f hf[9], hb[9];
        #pragma unroll
        for (int k = 0; k < 9; ++k) { hf[k] = hstv[base + k]; hb[k] = hstv[base + 9 + k]; }

        const int cA2 = pi2 * 2, cB2 = cA2 + 1;
        const int nA2 = cA2 / M_, mA2 = cA2 - nA2 * M_;
        const int nB2 = cB2 / M_, mB2 = cB2 - nB2 * M_;
        v2f vi;
        vi.x = (mA2 < numrec[nA2 * T_]) ? 1.f : 0.f;
        vi.y = (mB2 < numrec[nB2 * T_]) ? 1.f : 0.f;

        v2f q[9];
        #pragma unroll
        for (int dd = 0; dd < 9; ++dd) {
            v2f a = splat(lr1b[dd]);
            #pragma unroll
            for (int k = 0; k < 9; ++k) a += hf[k] * lr1W[dd*18 + k];
            #pragma unroll
            for (int k = 0; k < 9; ++k) a += hb[k] * lr1W[dd*18 + 9 + k];
            q[dd] = relu2(a);
        }
        float* opA = out + (size_t)((nA2 * T_ + t) * M_ + mA2) * 7;
        float* opB = out + (size_t)((nB2 * T_ + t) * M_ + mB2) * 7;
        #pragma unroll
        for (int j = 0; j < 7; ++j) {
            v2f a = splat(lr2b[j]);
            #pragma unroll
            for (int k = 0; k < 9; ++k) a += q[k] * lr2W[j*9 + k];
            a *= vi;
            opA[j] = a.x; opB[j] = a.y;
        }
    }
}

extern "C" void kernel_launch(void* const* d_in, const int* in_sizes, int n_in,
                              void* d_out, int out_size, void* d_ws, size_t ws_size,
                              hipStream_t stream) {
    const float* nf    = (const float*)d_in[0];
    const float* pos   = (const float*)d_in[1];
    const float* am    = (const float*)d_in[2];
    const float* msgW  = (const float*)d_in[3];
    const float* msgb  = (const float*)d_in[4];
    const float* gWih  = (const float*)d_in[5];
    const float* gWhh  = (const float*)d_in[6];
    const float* gbih  = (const float*)d_in[7];
    const float* gbhh  = (const float*)d_in[8];
    const float* ro1W  = (const float*)d_in[9];
    const float* ro1b  = (const float*)d_in[10];
    const float* ro2W  = (const float*)d_in[11];
    const float* ro2b  = (const float*)d_in[12];
    const float* lfWih = (const float*)d_in[13];
    const float* lfWhh = (const float*)d_in[14];
    const float* lfbih = (const float*)d_in[15];
    const float* lfbhh = (const float*)d_in[16];
    const float* lbWih = (const float*)d_in[17];
    const float* lbWhh = (const float*)d_in[18];
    const float* lbbih = (const float*)d_in[19];
    const float* lbbhh = (const float*)d_in[20];
    const float* lr1W  = (const float*)d_in[21];
    const float* lr1b  = (const float*)d_in[22];
    const float* lr2W  = (const float*)d_in[23];
    const float* lr2b  = (const float*)d_in[24];
    const int* numrec  = (const int*)d_in[25];

    // ws: hidden [nm][t][d] fp32 = 35,389,440 B
    float* hid = (float*)d_ws;

    float* outp = (float*)d_out;           // pred_label
    float* out0 = (float*)d_out + NTM7_;   // pred_label0

    // A: 20 (n,t) per single-wave block (2 per lane) -> 8192 blocks
    k_gnn <<<NT_ / 20, 64, 0, stream>>>(nf, pos, am, msgW, msgb, gWih, gWhh,
                                        gbih, gbhh, ro1W, ro1b, ro2W, ro2b,
                                        numrec, hid, out0);
    // B: 7 chain-pairs per two-wave block -> ceil(24576/7) = 3511 blocks
    const int lgrid = (NMP_ + 6) / 7;
    k_lstm<<<lgrid, 128, 0, stream>>>(hid, lfWih, lfWhh, lfbih, lfbhh,
                                      lbWih, lbWhh, lbbih, lbbhh,
                                      lr1W, lr1b, lr2W, lr2b, numrec, outp);
}

// Round 3
// 269.578 us; speedup vs baseline: 1.1266x; 1.0178x over previous
//
#include <hip/hip_runtime.h>

#define N_    8192
#define T_    20
#define M_    6
#define D_    9
#define NM_   (N_*M_)        // 49152 LSTM chains
#define NMP_  (NM_/2)        // 24576 chain PAIRS
#define NT_   (N_*T_)        // 163840 GNN problems
#define NTM7_ (N_*T_*M_*7)   // 6881280 elements per output tensor

#define LOG2E 1.44269504088896f

typedef __attribute__((ext_vector_type(2))) float v2f;

// native-rate activations: v_exp_f32 + v_rcp_f32 (no IEEE div sequence)
__device__ __forceinline__ float sigm(float x){
    return __builtin_amdgcn_rcpf(1.f + __builtin_amdgcn_exp2f(-LOG2E * x));
}
__device__ __forceinline__ float tanh_(float x){
    return fmaf(2.f, __builtin_amdgcn_rcpf(1.f + __builtin_amdgcn_exp2f(-2.f*LOG2E * x)), -1.f);
}
__device__ __forceinline__ v2f splat(float s){ return (v2f){s, s}; }
__device__ __forceinline__ v2f sigm2(v2f x){ v2f r; r.x = sigm(x.x); r.y = sigm(x.y); return r; }
__device__ __forceinline__ v2f tanh2(v2f x){ v2f r; r.x = tanh_(x.x); r.y = tanh_(x.y); return r; }
__device__ __forceinline__ v2f relu2(v2f x){ v2f r; r.x = fmaxf(x.x,0.f); r.y = fmaxf(x.y,0.f); return r; }

// ---------------------------------------------------------------------------
// Kernel A (R11): GNN — R8-verified per-wave code, TWO independent waves per
// block (each wave = one n, its own mbuf region; no barrier needed).
// Goal: more waves per resident block -> higher VALUBusy.
// ---------------------------------------------------------------------------
__global__ __launch_bounds__(128) void k_gnn(
    const float* __restrict__ nf,    // (N,T,M,3)
    const float* __restrict__ pos,   // (N,T,M,6)
    const float* __restrict__ am,    // (N,T,M,M)
    const float* __restrict__ msgW, const float* __restrict__ msgb,
    const float* __restrict__ gWih, const float* __restrict__ gWhh,
    const float* __restrict__ gbih, const float* __restrict__ gbhh,
    const float* __restrict__ ro1W, const float* __restrict__ ro1b,
    const float* __restrict__ ro2W, const float* __restrict__ ro2b,
    const int*   __restrict__ numrec,
    float* __restrict__ hid,         // [nm][t][d]
    float* __restrict__ out0)        // pred_label0 region
{
    __shared__ v2f mbuf[2][11 * 58]; // 10208 B; per-wave region; row 10 dummy

    const int wv   = threadIdx.x >> 6;
    const int lane = threadIdx.x & 63;
    const int g    = lane / 6;
    const int i    = lane - g * 6;
    const int gB   = g * 58;
    const bool lactive = (lane < 60);

    const int wbase = blockIdx.x * 40 + wv * 20;
    const int ntA = lactive ? (wbase + g)      : 0;
    const int ntB = lactive ? (wbase + 10 + g) : 0;
    const int nA = ntA / T_, tA = ntA - nA * T_;
    const int nB = ntB / T_, tB = ntB - nB * T_;

    v2f s[D_];
    {
        const float* pA = nf + (size_t)ntA * 18 + i * 3;
        const float* pB = nf + (size_t)ntB * 18 + i * 3;
        #pragma unroll
        for (int k = 0; k < 3; ++k) { s[k].x = pA[k]; s[k].y = pB[k]; }
    }
    {
        const float2* pA = (const float2*)(pos + (size_t)ntA * 36 + i * 6);
        const float2* pB = (const float2*)(pos + (size_t)ntB * 36 + i * 6);
        #pragma unroll
        for (int k = 0; k < 3; ++k) {
            float2 a = pA[k], b = pB[k];
            s[3 + 2*k]     = (v2f){a.x, b.x};
            s[3 + 2*k + 1] = (v2f){a.y, b.y};
        }
    }
    v2f attr[M_];
    {
        const float2* pA = (const float2*)(am + (size_t)ntA * 36 + i * 6);
        const float2* pB = (const float2*)(am + (size_t)ntB * 36 + i * 6);
        #pragma unroll
        for (int k = 0; k < 3; ++k) {
            float2 a = pA[k], b = pB[k];
            attr[2*k]     = (v2f){a.x, b.x};
            attr[2*k + 1] = (v2f){a.y, b.y};
        }
    }
    const int nrA = numrec[nA * T_];
    const int nrB = numrec[nB * T_];
    #pragma unroll
    for (int q = 0; q < M_; ++q) {
        attr[q].x *= (q < nrA) ? 1.f : 0.f;
        attr[q].y *= (q < nrB) ? 1.f : 0.f;
    }
    v2f vmi; vmi.x = (i < nrA) ? 1.f : 0.f; vmi.y = (i < nrB) ? 1.f : 0.f;

    #pragma unroll
    for (int it = 0; it < 2; ++it) {
        #pragma unroll
        for (int d = 0; d < D_; ++d) {
            v2f a = splat(msgb[d]);
            #pragma unroll
            for (int k = 0; k < D_; ++k) a += s[k] * msgW[d*9 + k];
            mbuf[wv][gB + d*6 + i] = a;
        }
        v2f mm[D_];
        #pragma unroll
        for (int d = 0; d < D_; ++d) {
            const float4* rp = (const float4*)&mbuf[wv][gB + d*6];
            float4 p0 = rp[0], p1 = rp[1], p2 = rp[2];
            v2f a = attr[0] * (v2f){p0.x, p0.y};
            a += attr[1] * (v2f){p0.z, p0.w};
            a += attr[2] * (v2f){p1.x, p1.y};
            a += attr[3] * (v2f){p1.z, p1.w};
            a += attr[4] * (v2f){p2.x, p2.y};
            a += attr[5] * (v2f){p2.z, p2.w};
            mm[d] = a;
        }
        v2f grz[18], gxn[9], ghn[9];
        #pragma unroll
        for (int j = 0; j < 18; ++j) {
            v2f a = splat(gbih[j] + gbhh[j]);
            #pragma unroll
            for (int k = 0; k < D_; ++k) {
                a += mm[k] * gWih[j*9 + k];
                a += s[k]  * gWhh[j*9 + k];
            }
            grz[j] = a;
        }
        #pragma unroll
        for (int j = 0; j < 9; ++j) {
            v2f ax = splat(gbih[18 + j]), ah = splat(gbhh[18 + j]);
            #pragma unroll
            for (int k = 0; k < D_; ++k) {
                ax += mm[k] * gWih[(18 + j)*9 + k];
                ah += s[k]  * gWhh[(18 + j)*9 + k];
            }
            gxn[j] = ax; ghn[j] = ah;
        }
        #pragma unroll
        for (int d = 0; d < D_; ++d) {
            v2f r  = sigm2(grz[d]);
            v2f z  = sigm2(grz[9 + d]);
            v2f nn = tanh2(gxn[d] + r * ghn[d]);
            s[d] = vmi * ((splat(1.f) - z) * nn + z * s[d]);
        }
    }

    if (lactive) {
        float* hpA = hid + (size_t)(nA * M_ + i) * (T_ * D_) + tA * D_;
        float* hpB = hid + (size_t)(nB * M_ + i) * (T_ * D_) + tB * D_;
        #pragma unroll
        for (int d = 0; d < D_; ++d) { hpA[d] = s[d].x; hpB[d] = s[d].y; }
    }

    v2f q9[D_];
    #pragma unroll
    for (int d = 0; d < D_; ++d) {
        v2f a = splat(ro1b[d]);
        #pragma unroll
        for (int k = 0; k < D_; ++k) a += s[k] * ro1W[d*9 + k];
        q9[d] = relu2(a);
    }
    if (lactive) {
        float* opA = out0 + (size_t)ntA * 42 + i * 7;
        float* opB = out0 + (size_t)ntB * 42 + i * 7;
        #pragma unroll
        for (int j = 0; j < 7; ++j) {
            v2f a = splat(ro2b[j]);
            #pragma unroll
            for (int k = 0; k < D_; ++k) a += q9[k] * ro2W[j*9 + k];
            a *= vmi;
            opA[j] = a.x; opB[j] = a.y;
        }
    }
}

// ---------------------------------------------------------------------------
// Kernel B (R11): bidirectional LSTM — R10's verified per-wave code, FOUR
// waves per block: (set,dir) = (wv>>1, wv&1); set 0/1 each own 7 pairs,
// dir 0 = forward scan, dir 1 = backward scan. 14 pairs/block, grid 1756.
// LDS = 4*1408 (per-wave hxs4) + 14*3048 (hstv) = 48304 B -> 3 blocks/CU
// = 12 waves/CU ceiling. Readout: 280 items over 256 threads, 2 rounds.
// Numerics identical to R10.
// ---------------------------------------------------------------------------
__global__ __launch_bounds__(256) void k_lstm(
    const float* __restrict__ hid,   // [nm][t][d]
    const float* __restrict__ fWih, const float* __restrict__ fWhh,
    const float* __restrict__ fbih, const float* __restrict__ fbhh,
    const float* __restrict__ bWih, const float* __restrict__ bWhh,
    const float* __restrict__ bbih, const float* __restrict__ bbhh,
    const float* __restrict__ lr1W, const float* __restrict__ lr1b,
    const float* __restrict__ lr2W, const float* __restrict__ lr2b,
    const int*   __restrict__ numrec,
    float* __restrict__ out)         // pred_label region
{
    __shared__ float4 hxs4[4][8 * 11]; // 5632 B: per-wave [row][j] {hA,hB,xA,xB}
    __shared__ v2f    hstv[14 * 381];  // 42672 B: [ch][t*19 + d]=hf, [..+9+d]=hb

    const int tid  = threadIdx.x;
    const int wv   = tid >> 6;                 // 0..3
    const int dir  = wv & 1;                   // 0 = forward, 1 = backward
    const int set  = wv >> 1;                  // 0/1: which 7 pairs
    const int lane = tid & 63;
    const int grp0 = lane / 9;                 // 0..7 (7 == lane 63 only)
    const int d    = lane - grp0 * 9;
    const int row  = grp0;

    bool active = (grp0 < 7);
    int pi = blockIdx.x * 14 + set * 7 + (active ? grp0 : 0);
    active = active && (pi < NMP_);
    const int pair = active ? pi : 0;
    const int cA = pair * 2, cB = cA + 1;

    const float* xbA = hid + (size_t)cA * (T_ * D_);
    const float* xbB = hid + (size_t)cB * (T_ * D_);
    const int  xrow   = row * 11;
    const bool hwrite = (grp0 < 7);            // lane 63 never writes hstv
    const int  hrow   = hwrite ? (set * 7 + row) * 381 : 0;

    if (dir == 0) {
        // ---------------- forward scan ----------------
        float wxi[9], wxf[9], wxg[9], wxo[9], whi[9], whf[9], whg[9], who[9];
        #pragma unroll
        for (int k = 0; k < 9; ++k) {
            wxi[k] = fWih[(d     )*9 + k];  whi[k] = fWhh[(d     )*9 + k];
            wxf[k] = fWih[(9  + d)*9 + k];  whf[k] = fWhh[(9  + d)*9 + k];
            wxg[k] = fWih[(18 + d)*9 + k];  whg[k] = fWhh[(18 + d)*9 + k];
            wxo[k] = fWih[(27 + d)*9 + k];  who[k] = fWhh[(27 + d)*9 + k];
        }
        const float bi = fbih[d]      + fbhh[d];
        const float bf = fbih[9 + d]  + fbhh[9 + d];
        const float bg = fbih[18 + d] + fbhh[18 + d];
        const float bo = fbih[27 + d] + fbhh[27 + d];

        hxs4[wv][xrow + d] = make_float4(0.f, 0.f, xbA[d], xbB[d]);  // {h(-1), x0}
        v2f h = splat(0.f), c = splat(0.f);
        for (int t = 0; t < T_; ++t) {
            const float xnA = (t < T_-1) ? xbA[(t+1)*9 + d] : 0.f;
            const float xnB = (t < T_-1) ? xbB[(t+1)*9 + d] : 0.f;
            v2f gi = splat(bi), gf = splat(bf), gg = splat(bg), go = splat(bo);
            #pragma unroll
            for (int j = 0; j < 9; ++j) {
                float4 v = hxs4[wv][xrow + j];             // broadcast b128
                v2f hj = (v2f){v.x, v.y}, xj = (v2f){v.z, v.w};
                gi += hj * whi[j]; gi += xj * wxi[j];
                gf += hj * whf[j]; gf += xj * wxf[j];
                gg += hj * whg[j]; gg += xj * wxg[j];
                go += hj * who[j]; go += xj * wxo[j];
            }
            c = sigm2(gf) * c + sigm2(gi) * tanh2(gg);
            h = sigm2(go) * tanh2(c);
            if (hwrite) hstv[hrow + t*19 + d] = h;         // save hf[t]
            hxs4[wv][xrow + d] = make_float4(h.x, h.y, xnA, xnB); // {h_t, x_{t+1}}
        }
    } else {
        // ---------------- backward scan ----------------
        float wxi[9], wxf[9], wxg[9], wxo[9], whi[9], whf[9], whg[9], who[9];
        #pragma unroll
        for (int k = 0; k < 9; ++k) {
            wxi[k] = bWih[(d     )*9 + k];  whi[k] = bWhh[(d     )*9 + k];
            wxf[k] = bWih[(9  + d)*9 + k];  whf[k] = bWhh[(9  + d)*9 + k];
            wxg[k] = bWih[(18 + d)*9 + k];  whg[k] = bWhh[(18 + d)*9 + k];
            wxo[k] = bWih[(27 + d)*9 + k];  who[k] = bWhh[(27 + d)*9 + k];
        }
        const float bi = bbih[d]      + bbhh[d];
        const float bf = bbih[9 + d]  + bbhh[9 + d];
        const float bg = bbih[18 + d] + bbhh[18 + d];
        const float bo = bbih[27 + d] + bbhh[27 + d];

        hxs4[wv][xrow + d] = make_float4(0.f, 0.f, xbA[19*9 + d], xbB[19*9 + d]);
        v2f h = splat(0.f), c = splat(0.f);
        for (int tt = T_ - 1; tt >= 0; --tt) {
            const float xnA = (tt > 0) ? xbA[(tt-1)*9 + d] : 0.f;
            const float xnB = (tt > 0) ? xbB[(tt-1)*9 + d] : 0.f;
            v2f gi = splat(bi), gf = splat(bf), gg = splat(bg), go = splat(bo);
            #pragma unroll
            for (int j = 0; j < 9; ++j) {
                float4 v = hxs4[wv][xrow + j];             // broadcast b128
                v2f hj = (v2f){v.x, v.y}, xj = (v2f){v.z, v.w};
                gi += hj * whi[j]; gi += xj * wxi[j];
                gf += hj * whf[j]; gf += xj * wxf[j];
                gg += hj * whg[j]; gg += xj * wxg[j];
                go += hj * who[j]; go += xj * wxo[j];
            }
            c = sigm2(gf) * c + sigm2(gi) * tanh2(gg);
            h = sigm2(go) * tanh2(c);                      // hb[tt]
            if (hwrite) hstv[hrow + tt*19 + 9 + d] = h;    // save hb[tt]
            hxs4[wv][xrow + d] = make_float4(h.x, h.y, xnA, xnB);
        }
    }

    __syncthreads();

    // ---------------- deferred readout (block-local pair-items) ----------------
    // 280 items per block: item -> (ch 0..13, t 0..19); each item outputs
    // BOTH chains of the pair. 256 threads -> 2 rounds.
    #pragma unroll 1
    for (int rr = 0; rr < 2; ++rr) {
        const int item = rr * 256 + tid;
        if (item >= 280) break;
        const int ch = item / 20;
        const int t  = item - ch * 20;
        const int pi2 = blockIdx.x * 14 + ch;
        if (pi2 >= NMP_) continue;
        const int base = ch * 381 + t * 19;

        v2f hf[9], hb[9];
        #pragma unroll
        for (int k = 0; k < 9; ++k) { hf[k] = hstv[base + k]; hb[k] = hstv[base + 9 + k]; }

        const int cA2 = pi2 * 2, cB2 = cA2 + 1;
        const int nA2 = cA2 / M_, mA2 = cA2 - nA2 * M_;
        const int nB2 = cB2 / M_, mB2 = cB2 - nB2 * M_;
        v2f vi;
        vi.x = (mA2 < numrec[nA2 * T_]) ? 1.f : 0.f;
        vi.y = (mB2 < numrec[nB2 * T_]) ? 1.f : 0.f;

        v2f q[9];
        #pragma unroll
        for (int dd = 0; dd < 9; ++dd) {
            v2f a = splat(lr1b[dd]);
            #pragma unroll
            for (int k = 0; k < 9; ++k) a += hf[k] * lr1W[dd*18 + k];
            #pragma unroll
            for (int k = 0; k < 9; ++k) a += hb[k] * lr1W[dd*18 + 9 + k];
            q[dd] = relu2(a);
        }
        float* opA = out + (size_t)((nA2 * T_ + t) * M_ + mA2) * 7;
        float* opB = out + (size_t)((nB2 * T_ + t) * M_ + mB2) * 7;
        #pragma unroll
        for (int j = 0; j < 7; ++j) {
            v2f a = splat(lr2b[j]);
            #pragma unroll
            for (int k = 0; k < 9; ++k) a += q[k] * lr2W[j*9 + k];
            a *= vi;
            opA[j] = a.x; opB[j] = a.y;
        }
    }
}

extern "C" void kernel_launch(void* const* d_in, const int* in_sizes, int n_in,
                              void* d_out, int out_size, void* d_ws, size_t ws_size,
                              hipStream_t stream) {
    const float* nf    = (const float*)d_in[0];
    const float* pos   = (const float*)d_in[1];
    const float* am    = (const float*)d_in[2];
    const float* msgW  = (const float*)d_in[3];
    const float* msgb  = (const float*)d_in[4];
    const float* gWih  = (const float*)d_in[5];
    const float* gWhh  = (const float*)d_in[6];
    const float* gbih  = (const float*)d_in[7];
    const float* gbhh  = (const float*)d_in[8];
    const float* ro1W  = (const float*)d_in[9];
    const float* ro1b  = (const float*)d_in[10];
    const float* ro2W  = (const float*)d_in[11];
    const float* ro2b  = (const float*)d_in[12];
    const float* lfWih = (const float*)d_in[13];
    const float* lfWhh = (const float*)d_in[14];
    const float* lfbih = (const float*)d_in[15];
    const float* lfbhh = (const float*)d_in[16];
    const float* lbWih = (const float*)d_in[17];
    const float* lbWhh = (const float*)d_in[18];
    const float* lbbih = (const float*)d_in[19];
    const float* lbbhh = (const float*)d_in[20];
    const float* lr1W  = (const float*)d_in[21];
    const float* lr1b  = (const float*)d_in[22];
    const float* lr2W  = (const float*)d_in[23];
    const float* lr2b  = (const float*)d_in[24];
    const int* numrec  = (const int*)d_in[25];

    // ws: hidden [nm][t][d] fp32 = 35,389,440 B
    float* hid = (float*)d_ws;

    float* outp = (float*)d_out;           // pred_label
    float* out0 = (float*)d_out + NTM7_;   // pred_label0

    // A: 40 (n,t) per two-wave block (one n per wave) -> 4096 blocks
    k_gnn <<<NT_ / 40, 128, 0, stream>>>(nf, pos, am, msgW, msgb, gWih, gWhh,
                                         gbih, gbhh, ro1W, ro1b, ro2W, ro2b,
                                         numrec, hid, out0);
    // B: 14 chain-pairs per four-wave block -> ceil(24576/14) = 1756 blocks
    const int lgrid = (NMP_ + 13) / 14;
    k_lstm<<<lgrid, 256, 0, stream>>>(hid, lfWih, lfWhh, lfbih, lfbhh,
                                      lbWih, lbWhh, lbbih, lbbhh,
                                      lr1W, lr1b, lr2W, lr2b, numrec, outp);
}